// Round 3
// baseline (541.963 us; speedup 1.0000x reference)
//
#include <hip/hip_runtime.h>
#include <math.h>

// Problem constants
#define BB   8
#define TT   16
#define HH   64
#define WW   64
#define CINc 32
#define FFc  32
#define GG   128          // 4*F gate channels
#define KK   576          // 9 taps * 64 ci
#define PSTR 72           // LDS fp16 stride (64 + 8 pad)
#define GSTR 68           // gate-buffer fp32 px stride (64 + 4 pad)

typedef _Float16 half8 __attribute__((ext_vector_type(8)));
typedef float    f32x4 __attribute__((ext_vector_type(4)));

__device__ __forceinline__ float fast_tanh(float v) {
    float e = __expf(2.f * v);
    return 1.f - 2.f / (e + 1.f);
}
__device__ __forceinline__ float hsig(float v) {
    return fminf(fmaxf(0.2f * v + 0.5f, 0.f), 1.f);
}

// Pack weights tap-major: Wt2[tap][n][ci], ci<32 from Wx, else Wh.
__global__ void prep_w(const float* __restrict__ Wx, const float* __restrict__ Wh,
                       _Float16* __restrict__ Wt2) {
    const int k = blockIdx.x;      // 0..575 = tap*64 + ci
    const int n = threadIdx.x;     // 0..127
    const int tap = k >> 6, ci = k & 63;
    const float v = (ci < 32) ? Wx[(tap * 32 + ci) * GG + n]
                              : Wh[(tap * 32 + (ci - 32)) * GG + n];
    Wt2[((size_t)tap * GG + n) * 64 + ci] = (_Float16)v;
}

// One timestep. Block: 4x16 px tile (64 px) x 128 gate-ch, 256 threads (4 waves).
// Wave (pxg = w>>1, chg = w&1): 32 px (rows 2*pxg..+1) x 64 ch -> 2x4 MFMA acc tiles.
__global__ __launch_bounds__(256, 2)
void convlstm_step(const float* __restrict__ x,        // [B,T,H,W,32] fp32
                   const _Float16* __restrict__ Wt2,   // [9][128][64] fp16
                   const float* __restrict__ bias,     // [128]
                   const float* __restrict__ gamma_,   // [32]
                   const float* __restrict__ beta_,    // [32]
                   const float* __restrict__ mmean,    // [32]
                   const float* __restrict__ mvar,     // [32]
                   const _Float16* __restrict__ hprev, // [B,H,W,32] fp16
                   _Float16* __restrict__ hnext,       // [B,H,W,32] fp16
                   float* __restrict__ cstate,         // [B,H,W,32] fp32
                   float* __restrict__ out,            // [B,T,H,W,32] fp32
                   int t)
{
    __shared__ union USmem {
        struct { _Float16 patch[108 * PSTR]; _Float16 wbuf[2][GG * PSTR]; } s;
        float gbuf[GG * GSTR];   // epilogue gate buffer [ch][px] (overlays patch/wbuf)
    } u;

    const int tid  = threadIdx.x;
    const int lane = tid & 63;
    const int w    = tid >> 6;
    const int l15  = lane & 15;
    const int quad = lane >> 4;
    const int chg  = w & 1;
    const int pxg  = w >> 1;
    const int px0  = blockIdx.x * 16;   // 0..48
    const int py0  = blockIdx.y * 4;    // 0..60
    const int b    = blockIdx.z;

    const float*    xt = x     + (((size_t)b * TT + t) * HH * WW) * CINc;
    const _Float16* hp = hprev + ((size_t)b * HH * WW) * FFc;

    // ---- patch staging: 6x18 halo positions, 8 slots of 8 ch (x fp32->fp16 | h fp16) ----
    for (int i = tid; i < 108 * 8; i += 256) {
        const int pos  = i >> 3;
        const int slot = i & 7;
        const int row  = pos / 18;
        const int col  = pos - row * 18;
        const int gy = py0 + row - 1;
        const int gx = px0 + col - 1;
        const bool ok = ((unsigned)gy < HH) && ((unsigned)gx < WW);
        half8 hv = {0, 0, 0, 0, 0, 0, 0, 0};
        if (slot < 4) {
            if (ok) {
                const float* s = xt + ((size_t)(gy * WW + gx)) * CINc + slot * 8;
                const float4 v0 = *(const float4*)s;
                const float4 v1 = *(const float4*)(s + 4);
                hv = (half8){(_Float16)v0.x, (_Float16)v0.y, (_Float16)v0.z, (_Float16)v0.w,
                             (_Float16)v1.x, (_Float16)v1.y, (_Float16)v1.z, (_Float16)v1.w};
            }
        } else {
            if (ok) hv = *(const half8*)(hp + ((size_t)(gy * WW + gx)) * FFc + (slot - 4) * 8);
        }
        *(half8*)&u.s.patch[pos * PSTR + slot * 8] = hv;
    }

    // ---- stage tap-0 weights (16 KB contiguous) ----
    #pragma unroll
    for (int i = 0; i < 4; ++i) {
        const int c = tid + i * 256;
        const int n = c >> 3, sub = c & 7;
        *(uint4*)&u.s.wbuf[0][n * PSTR + sub * 8] =
            *(const uint4*)(Wt2 + (size_t)n * 64 + sub * 8);
    }
    __syncthreads();

    f32x4 acc[2][4];
    #pragma unroll
    for (int mt = 0; mt < 2; ++mt)
        #pragma unroll
        for (int nt = 0; nt < 4; ++nt)
            acc[mt][nt] = (f32x4){0.f, 0.f, 0.f, 0.f};

    // ---- K loop: 9 taps x 2 ksteps (K=32) ----
    for (int tap = 0; tap < 9; ++tap) {
        const int buf = tap & 1;
        uint4 pre[4];
        if (tap < 8) {
            const _Float16* wsrc = Wt2 + ((size_t)(tap + 1) * GG) * 64;
            #pragma unroll
            for (int i = 0; i < 4; ++i) {
                const int c = tid + i * 256;
                const int n = c >> 3, sub = c & 7;
                pre[i] = *(const uint4*)(wsrc + (size_t)n * 64 + sub * 8);
            }
        }
        const int ky = tap / 3;
        const int kx = tap - ky * 3;

        #pragma unroll
        for (int hk = 0; hk < 2; ++hk) {
            const int ci0 = hk * 32 + quad * 8;
            const half8 a0 = *(const half8*)&u.s.patch[((pxg * 2 + 0 + ky) * 18 + l15 + kx) * PSTR + ci0];
            const half8 a1 = *(const half8*)&u.s.patch[((pxg * 2 + 1 + ky) * 18 + l15 + kx) * PSTR + ci0];
            half8 bf[4];
            #pragma unroll
            for (int nt = 0; nt < 4; ++nt)
                bf[nt] = *(const half8*)&u.s.wbuf[buf][(chg * 64 + nt * 16 + l15) * PSTR + ci0];
            #pragma unroll
            for (int nt = 0; nt < 4; ++nt) {
                acc[0][nt] = __builtin_amdgcn_mfma_f32_16x16x32_f16(a0, bf[nt], acc[0][nt], 0, 0, 0);
                acc[1][nt] = __builtin_amdgcn_mfma_f32_16x16x32_f16(a1, bf[nt], acc[1][nt], 0, 0, 0);
            }
        }
        if (tap < 8) {
            #pragma unroll
            for (int i = 0; i < 4; ++i) {
                const int c = tid + i * 256;
                const int n = c >> 3, sub = c & 7;
                *(uint4*)&u.s.wbuf[1 - buf][n * PSTR + sub * 8] = pre[i];
            }
        }
        __syncthreads();
    }

    // ---- write acc to gate buffer [ch][px] (vector, aligned; overlays dead patch/wbuf) ----
    #pragma unroll
    for (int mt = 0; mt < 2; ++mt) {
        const int pxb = (pxg * 2 + mt) * 16 + quad * 4;
        #pragma unroll
        for (int nt = 0; nt < 4; ++nt) {
            const int ch = chg * 64 + nt * 16 + l15;
            *(f32x4*)&u.gbuf[ch * GSTR + pxb] = acc[mt][nt];
        }
    }
    __syncthreads();

    // ---- epilogue: thread = 1 px x 8 features; gates i|f|c|o at ch f, f+32, f+64, f+96 ----
    const int p    = tid >> 2;          // px in block
    const int fb   = (tid & 3) * 8;     // feature base
    const int prow = p >> 4, pcol = p & 15;
    const size_t pixg = (size_t)((py0 + prow) * WW + px0 + pcol);
    const size_t sidx = ((size_t)b * HH * WW + pixg) * FFc + fb;
    float* oq = out + ((((size_t)b * TT + t) * HH * WW) + pixg) * FFc + fb;

    float gi[8], gf[8], gc[8], go[8];
    #pragma unroll
    for (int j = 0; j < 8; ++j) {
        const int f = fb + j;
        gi[j] = u.gbuf[(f     ) * GSTR + p] + bias[f];
        gf[j] = u.gbuf[(f + 32) * GSTR + p] + bias[f + 32];
        gc[j] = u.gbuf[(f + 64) * GSTR + p] + bias[f + 64];
        go[j] = u.gbuf[(f + 96) * GSTR + p] + bias[f + 96];
    }

    const float4 co0 = *(const float4*)(cstate + sidx);
    const float4 co1 = *(const float4*)(cstate + sidx + 4);
    const float cold[8] = {co0.x, co0.y, co0.z, co0.w, co1.x, co1.y, co1.z, co1.w};

    float cn[8], hn[8], on[8];
    #pragma unroll
    for (int j = 0; j < 8; ++j) {
        const int f = fb + j;
        const float inv = gamma_[f] * rsqrtf(mvar[f] + 1e-3f);
        const float bnb = beta_[f] - mmean[f] * inv;
        cn[j] = hsig(gf[j]) * cold[j] + hsig(gi[j]) * fast_tanh(gc[j]);
        hn[j] = hsig(go[j]) * fast_tanh(cn[j]);
        on[j] = hn[j] * inv + bnb;
    }

    *(float4*)(cstate + sidx)     = make_float4(cn[0], cn[1], cn[2], cn[3]);
    *(float4*)(cstate + sidx + 4) = make_float4(cn[4], cn[5], cn[6], cn[7]);
    *(half8*)(hnext + sidx) = (half8){(_Float16)hn[0], (_Float16)hn[1], (_Float16)hn[2], (_Float16)hn[3],
                                      (_Float16)hn[4], (_Float16)hn[5], (_Float16)hn[6], (_Float16)hn[7]};
    *(float4*)(oq)     = make_float4(on[0], on[1], on[2], on[3]);
    *(float4*)(oq + 4) = make_float4(on[4], on[5], on[6], on[7]);
}

extern "C" void kernel_launch(void* const* d_in, const int* in_sizes, int n_in,
                              void* d_out, int out_size, void* d_ws, size_t ws_size,
                              hipStream_t stream)
{
    const float* x      = (const float*)d_in[0];
    const float* Wx     = (const float*)d_in[1];
    const float* Wh     = (const float*)d_in[2];
    const float* bias   = (const float*)d_in[3];
    const float* gamma_ = (const float*)d_in[4];
    const float* beta_  = (const float*)d_in[5];
    const float* mmean  = (const float*)d_in[6];
    const float* mvar   = (const float*)d_in[7];
    float* out = (float*)d_out;

    // ws layout: [h0 fp16 2MB][c fp32 4MB][h1 fp16 2MB][Wt2 fp16 147KB]
    char* wsb = (char*)d_ws;
    _Float16* h0  = (_Float16*)wsb;
    float*    cs  = (float*)(wsb + (2 << 20));
    _Float16* h1  = (_Float16*)(wsb + (6 << 20));
    _Float16* Wt2 = (_Float16*)(wsb + (8 << 20));

    hipMemsetAsync(d_ws, 0, (size_t)6 << 20, stream);   // zero h0 + c
    prep_w<<<dim3(KK), dim3(GG), 0, stream>>>(Wx, Wh, Wt2);

    dim3 grid(WW / 16, HH / 4, BB);   // (4,16,8) = 512 blocks -> 2 per CU
    _Float16* hprev = h0;
    _Float16* hnext = h1;
    for (int t = 0; t < TT; ++t) {
        convlstm_step<<<grid, 256, 0, stream>>>(x, Wt2, bias, gamma_, beta_,
                                                mmean, mvar, hprev, hnext, cs, out, t);
        _Float16* tmp = hprev; hprev = hnext; hnext = tmp;
    }
}